// Round 4
// baseline (442.320 us; speedup 1.0000x reference)
//
#include <hip/hip_runtime.h>

// Problem constants (from reference)
#define VOCAB   35097
#define DDIM    300
#define NWORDS  3000
#define L_SIG   900000          // DDIM * NWORDS
#define NFILT   100
#define NCLS    10

// Tiling: QQ positions per lane. Grid sized for occupancy: 879*2 = 1758
// blocks ~= 6.9 blocks/CU (vs 3.4 last round) -> ~7 waves/SIMD resident.
#define QQ      16
#define WIN     (QQ + 4)        // 20 floats per lane window
#define BLK_POS (64 * QQ)       // 1024 positions per block
#define NBLK    879             // 879*1024 = 900096 >= 899998; block 878 is TAIL

__device__ __forceinline__ float relu_(float v) { return fmaxf(v, 0.0f); }

// One filter's weights+biases as NAMED members (nothing runtime-indexed ->
// cannot be demoted to scratch; r3's array version spilled, VGPR=28 < h[]).
struct Wf {
  float a0, a1, a2;               // conv3
  float c0, c1, c2, c3;           // conv4
  float e0, e1, e2, e3, e4;       // conv5
  float bb3, bb4, bb5;            // biases
};

// readfirstlane makes the filter index provably wave-uniform -> s_load.
__device__ __forceinline__ Wf load_wf(
    int f,
    const float* __restrict__ w1, const float* __restrict__ b1,
    const float* __restrict__ w2, const float* __restrict__ b2,
    const float* __restrict__ w3, const float* __restrict__ b3)
{
  const int fu = __builtin_amdgcn_readfirstlane(f);
  const float* p1 = w1 + fu * 3;
  const float* p2 = w2 + fu * 4;
  const float* p3 = w3 + fu * 5;
  Wf W;
  W.a0 = p1[0]; W.a1 = p1[1]; W.a2 = p1[2];
  W.c0 = p2[0]; W.c1 = p2[1]; W.c2 = p2[2]; W.c3 = p2[3];
  W.e0 = p3[0]; W.e1 = p3[1]; W.e2 = p3[2]; W.e3 = p3[3]; W.e4 = p3[4];
  W.bb3 = b1[fu]; W.bb4 = b2[fu]; W.bb5 = b3[fu];
  return W;
}

// Each wave: 25 filters x 3 conv sizes over its 64*QQ position tile.
// Bias+ReLU deferred past the max (both monotone). TAIL only in block 878.
template<bool TAIL>
__device__ __forceinline__ void run_filters(
    const float (&h)[WIN], int t0, int wave, int batch, int lane,
    const float* __restrict__ w1, const float* __restrict__ b1,
    const float* __restrict__ w2, const float* __restrict__ b2,
    const float* __restrict__ w3, const float* __restrict__ b3,
    unsigned int* __restrict__ acc)
{
  int n3 = QQ, n4 = QQ, n5 = QQ;
  if (TAIL) {
    n3 = min(max(899998 - t0, 0), QQ);   // conv3 valid t <= 899997
    n4 = min(max(899997 - t0, 0), QQ);   // conv4 valid t <= 899996
    n5 = min(max(899996 - t0, 0), QQ);   // conv5 valid t <= 899995
  }
  const float NEG = -__builtin_huge_valf();
  const int fbase = wave * 25;

  Wf W = load_wf(fbase, w1, b1, w2, b2, w3, b3);   // prologue: filter 0

  #pragma unroll 1   // one copy of the (fully unrolled) p-loop body
  for (int i = 0; i < 25; ++i) {
    // Software pipeline: issue next filter's s_loads now; their lgkm wait
    // lands ~300 VALU instructions later. Clamped index keeps it branchless.
    Wf Wn = load_wf(fbase + ((i < 24) ? i + 1 : i), w1, b1, w2, b2, w3, b3);

    float m3[2] = {NEG, NEG}, m4[2] = {NEG, NEG}, m5[2] = {NEG, NEG};

    if (!TAIL) {
      // Pairs of positions; fmaxf(fmaxf(m,va),vb) fuses to v_max3_f32.
      #pragma unroll
      for (int p = 0; p < QQ; p += 2) {
        const int q = (p >> 1) & 1;
        float v3a = fmaf(W.a0, h[p],   fmaf(W.a1, h[p+1], W.a2 * h[p+2]));
        float v3b = fmaf(W.a0, h[p+1], fmaf(W.a1, h[p+2], W.a2 * h[p+3]));
        m3[q] = fmaxf(fmaxf(m3[q], v3a), v3b);
        float v4a = fmaf(W.c0, h[p],   fmaf(W.c1, h[p+1], fmaf(W.c2, h[p+2], W.c3 * h[p+3])));
        float v4b = fmaf(W.c0, h[p+1], fmaf(W.c1, h[p+2], fmaf(W.c2, h[p+3], W.c3 * h[p+4])));
        m4[q] = fmaxf(fmaxf(m4[q], v4a), v4b);
        float v5a = fmaf(W.e0, h[p],   fmaf(W.e1, h[p+1], fmaf(W.e2, h[p+2], fmaf(W.e3, h[p+3], W.e4 * h[p+4]))));
        float v5b = fmaf(W.e0, h[p+1], fmaf(W.e1, h[p+2], fmaf(W.e2, h[p+3], fmaf(W.e3, h[p+4], W.e4 * h[p+5]))));
        m5[q] = fmaxf(fmaxf(m5[q], v5a), v5b);
      }
    } else {
      #pragma unroll
      for (int p = 0; p < QQ; ++p) {
        const int q = p & 1;
        float v3 = fmaf(W.a0, h[p], fmaf(W.a1, h[p+1], W.a2 * h[p+2]));
        float v4 = fmaf(W.c0, h[p], fmaf(W.c1, h[p+1], fmaf(W.c2, h[p+2], W.c3 * h[p+3])));
        float v5 = fmaf(W.e0, h[p], fmaf(W.e1, h[p+1], fmaf(W.e2, h[p+2], fmaf(W.e3, h[p+3], W.e4 * h[p+4]))));
        if (p < n3) m3[q] = fmaxf(m3[q], v3);
        if (p < n4) m4[q] = fmaxf(m4[q], v4);
        if (p < n5) m5[q] = fmaxf(m5[q], v5);
      }
    }
    float r3 = fmaxf(m3[0], m3[1]);
    float r4 = fmaxf(m4[0], m4[1]);
    float r5 = fmaxf(m5[0], m5[1]);

    // wave-level max reduce (64 lanes)
    #pragma unroll
    for (int s = 1; s < 64; s <<= 1) {
      r3 = fmaxf(r3, __shfl_xor(r3, s));
      r4 = fmaxf(r4, __shfl_xor(r4, s));
      r5 = fmaxf(r5, __shfl_xor(r5, s));
    }
    if (lane == 0) {
      unsigned int* ab = acc + batch * 3 * NFILT;
      const int f = fbase + i;
      // post-ReLU values are >= 0 -> uint bit pattern is order-preserving
      atomicMax(ab + f,             __float_as_uint(relu_(r3 + W.bb3)));
      atomicMax(ab + NFILT + f,     __float_as_uint(relu_(r4 + W.bb4)));
      atomicMax(ab + 2 * NFILT + f, __float_as_uint(relu_(r5 + W.bb5)));
    }
    W = Wn;   // rotate preloaded scalars (SALU movs)
  }
}

__global__ __launch_bounds__(256) void conv_max_kernel(
    const int* __restrict__ x, const float* __restrict__ emb,
    const float* __restrict__ w1, const float* __restrict__ b1,
    const float* __restrict__ w2, const float* __restrict__ b2,
    const float* __restrict__ w3, const float* __restrict__ b3,
    unsigned int* __restrict__ acc)
{
  const int lane  = threadIdx.x & 63;
  const int wave  = threadIdx.x >> 6;
  const int batch = blockIdx.y;
  const int t0_blk = blockIdx.x * BLK_POS;
  const int t0     = t0_blk + lane * QQ;

  // Gather the signal window [t0, t0+WIN) directly from emb.
  // t0 % 4 == 0 and DDIM % 4 == 0 -> float4-aligned; WIN=20 <= DDIM so the
  // window spans at most 2 embedding rows.
  float h[WIN];
  {
    int w0 = t0 / DDIM;
    int d0 = t0 - w0 * DDIM;                 // multiple of 4
    int wa = min(w0, NWORDS - 1);            // clamp: OOB lanes masked in TAIL path
    int wb = min(w0 + 1, NWORDS - 1);
    int xa = x[batch * NWORDS + wa];
    int xb = x[batch * NWORDS + wb];
    const float4* rowA = (const float4*)(emb + (size_t)xa * DDIM) + (d0 >> 2);
    const float4* rowB = (const float4*)(emb + (size_t)xb * DDIM);
    const int nf4 = (DDIM - d0) >> 2;        // float4s remaining in word A
    #pragma unroll
    for (int i = 0; i < WIN / 4; ++i) {
      const float4* src = (i < nf4) ? (rowA + i) : (rowB + (i - nf4));
      float4 v = *src;
      h[4*i+0] = v.x; h[4*i+1] = v.y; h[4*i+2] = v.z; h[4*i+3] = v.w;
    }
  }

  const bool tail = (t0_blk + BLK_POS + 4) > L_SIG;   // only block 878
  if (tail)
    run_filters<true >(h, t0, wave, batch, lane, w1, b1, w2, b2, w3, b3, acc);
  else
    run_filters<false>(h, t0, wave, batch, lane, w1, b1, w2, b2, w3, b3, acc);
}

// out[b][c] = sum_j feats[b][j] * fc_w[c][j] + fc_b[c];  feats = relu'd maxes in acc
__global__ void fc_kernel(const unsigned int* __restrict__ acc,
                          const float* __restrict__ fcw,
                          const float* __restrict__ fcb,
                          float* __restrict__ out)
{
  const int b = blockIdx.x / NCLS;
  const int c = blockIdx.x % NCLS;
  const int lane = threadIdx.x;
  float s = 0.0f;
  for (int j = lane; j < 3 * NFILT; j += 64)
    s += __uint_as_float(acc[b * 3 * NFILT + j]) * fcw[c * 3 * NFILT + j];
  #pragma unroll
  for (int k = 1; k < 64; k <<= 1) s += __shfl_xor(s, k);
  if (lane == 0) out[b * NCLS + c] = s + fcb[c];
}

extern "C" void kernel_launch(void* const* d_in, const int* in_sizes, int n_in,
                              void* d_out, int out_size, void* d_ws, size_t ws_size,
                              hipStream_t stream)
{
  const int*   x   = (const int*)  d_in[0];
  const float* emb = (const float*)d_in[1];
  const float* w1  = (const float*)d_in[2];
  const float* b1  = (const float*)d_in[3];
  const float* w2  = (const float*)d_in[4];
  const float* b2  = (const float*)d_in[5];
  const float* w3  = (const float*)d_in[6];
  const float* b3  = (const float*)d_in[7];
  const float* fcw = (const float*)d_in[8];
  const float* fcb = (const float*)d_in[9];
  float* out = (float*)d_out;

  unsigned int* acc = (unsigned int*)d_ws;   // [2][3][100] relu'd maxes as uint bits

  // ReLU output >= 0, so 0-init is the identity for the uint atomicMax.
  hipMemsetAsync(acc, 0, 2 * 3 * NFILT * sizeof(unsigned int), stream);

  dim3 grid(NBLK, 2);
  conv_max_kernel<<<grid, 256, 0, stream>>>(x, emb, w1, b1, w2, b2, w3, b3, acc);
  fc_kernel<<<2 * NCLS, 64, 0, stream>>>(acc, fcw, fcb, out);
}

// Round 5
// 351.000 us; speedup vs baseline: 1.2602x; 1.2602x over previous
//
#include <hip/hip_runtime.h>

// Problem constants (from reference)
#define VOCAB   35097
#define DDIM    300
#define NWORDS  3000
#define L_SIG   900000          // DDIM * NWORDS
#define NFILT   100
#define NCLS    10

// Tiling.
//  - QQ positions per lane (multiple of 4; paired for v_max3 fusion).
//  - FPW filters per wave, FULLY UNROLLED so the 3*FPW running maxes are
//    statically indexed registers (runtime-indexed arrays -> scratch; that
//    poisoned rounds 3/4).
//  - Filters split over gridDim.z groups: per-wave reduce happens ONCE per
//    tile instead of once per filter (rounds 2-4's dominant overhead: a
//    serialized 6-deep shuffle chain per filter).
#define QQ      32
#define WIN     (QQ + 4)        // 36 floats per lane window
#define BLK_POS (64 * QQ)       // 2048 positions per block
#define NBLK    440             // 440*2048 = 901120 >= 899998; block 439 = TAIL
#define FPW     5               // filters per wave
#define NGRP    5               // gridDim.z; 4 waves * FPW * NGRP = 100 filters

__device__ __forceinline__ float relu_(float v) { return fmaxf(v, 0.0f); }

// Each wave: FPW filters x 3 conv sizes over its 64*QQ position tile,
// accumulating per-lane maxes in registers; ONE butterfly reduce at the end.
// Bias+ReLU deferred past the max (both monotone). TAIL only in block 439.
template<bool TAIL>
__device__ __forceinline__ void run_filters(
    const float (&h)[WIN], int t0, int f0, int batch,
    const float* __restrict__ w1, const float* __restrict__ b1,
    const float* __restrict__ w2, const float* __restrict__ b2,
    const float* __restrict__ w3, const float* __restrict__ b3,
    unsigned int* __restrict__ acc)
{
  int n3 = QQ, n4 = QQ, n5 = QQ;
  if (TAIL) {
    n3 = min(max(899998 - t0, 0), QQ);   // conv3 valid t <= 899997
    n4 = min(max(899997 - t0, 0), QQ);   // conv4 valid t <= 899996
    n5 = min(max(899996 - t0, 0), QQ);   // conv5 valid t <= 899995
  }
  const float NEG = -__builtin_huge_valf();

  float acc3[FPW], acc4[FPW], acc5[FPW];   // static indexing only (unrolled)

  #pragma unroll
  for (int j = 0; j < FPW; ++j) {
    // Wave-uniform filter index -> s_load weights into SGPRs. Fully static
    // unroll lets the scheduler hoist these loads ahead of use.
    const int fu = __builtin_amdgcn_readfirstlane(f0 + j);
    const float a0 = w1[fu*3+0], a1 = w1[fu*3+1], a2 = w1[fu*3+2];
    const float c0 = w2[fu*4+0], c1 = w2[fu*4+1], c2 = w2[fu*4+2], c3 = w2[fu*4+3];
    const float e0 = w3[fu*5+0], e1 = w3[fu*5+1], e2 = w3[fu*5+2], e3 = w3[fu*5+3], e4 = w3[fu*5+4];

    float m3a = NEG, m3b = NEG, m4a = NEG, m4b = NEG, m5a = NEG, m5b = NEG;

    if (!TAIL) {
      // Pairs of positions; fmaxf(fmaxf(m,va),vb) fuses to v_max3_f32.
      #pragma unroll
      for (int p = 0; p < QQ; p += 2) {
        float v3a = fmaf(a0, h[p],   fmaf(a1, h[p+1], a2 * h[p+2]));
        float v3b = fmaf(a0, h[p+1], fmaf(a1, h[p+2], a2 * h[p+3]));
        if (((p >> 1) & 1) == 0) m3a = fmaxf(fmaxf(m3a, v3a), v3b);
        else                     m3b = fmaxf(fmaxf(m3b, v3a), v3b);
        float v4a = fmaf(c0, h[p],   fmaf(c1, h[p+1], fmaf(c2, h[p+2], c3 * h[p+3])));
        float v4b = fmaf(c0, h[p+1], fmaf(c1, h[p+2], fmaf(c2, h[p+3], c3 * h[p+4])));
        if (((p >> 1) & 1) == 0) m4a = fmaxf(fmaxf(m4a, v4a), v4b);
        else                     m4b = fmaxf(fmaxf(m4b, v4a), v4b);
        float v5a = fmaf(e0, h[p],   fmaf(e1, h[p+1], fmaf(e2, h[p+2], fmaf(e3, h[p+3], e4 * h[p+4]))));
        float v5b = fmaf(e0, h[p+1], fmaf(e1, h[p+2], fmaf(e2, h[p+3], fmaf(e3, h[p+4], e4 * h[p+5]))));
        if (((p >> 1) & 1) == 0) m5a = fmaxf(fmaxf(m5a, v5a), v5b);
        else                     m5b = fmaxf(fmaxf(m5b, v5a), v5b);
      }
    } else {
      #pragma unroll
      for (int p = 0; p < QQ; ++p) {
        float v3 = fmaf(a0, h[p], fmaf(a1, h[p+1], a2 * h[p+2]));
        float v4 = fmaf(c0, h[p], fmaf(c1, h[p+1], fmaf(c2, h[p+2], c3 * h[p+3])));
        float v5 = fmaf(e0, h[p], fmaf(e1, h[p+1], fmaf(e2, h[p+2], fmaf(e3, h[p+3], e4 * h[p+4]))));
        if (p < n3) { if (p & 1) m3b = fmaxf(m3b, v3); else m3a = fmaxf(m3a, v3); }
        if (p < n4) { if (p & 1) m4b = fmaxf(m4b, v4); else m4a = fmaxf(m4a, v4); }
        if (p < n5) { if (p & 1) m5b = fmaxf(m5b, v5); else m5a = fmaxf(m5a, v5); }
      }
    }
    acc3[j] = fmaxf(m3a, m3b);
    acc4[j] = fmaxf(m4a, m4b);
    acc5[j] = fmaxf(m5a, m5b);
  }

  // ONE batched wave reduction: 3*FPW independent 6-level chains (ILP hides
  // the shuffle latency that dominated rounds 2-4 when paid per filter).
  #pragma unroll
  for (int s = 1; s < 64; s <<= 1) {
    #pragma unroll
    for (int j = 0; j < FPW; ++j) {
      acc3[j] = fmaxf(acc3[j], __shfl_xor(acc3[j], s));
      acc4[j] = fmaxf(acc4[j], __shfl_xor(acc4[j], s));
      acc5[j] = fmaxf(acc5[j], __shfl_xor(acc5[j], s));
    }
  }

  if ((threadIdx.x & 63) == 0) {
    unsigned int* ab = acc + batch * 3 * NFILT;
    #pragma unroll
    for (int j = 0; j < FPW; ++j) {
      const int fu = __builtin_amdgcn_readfirstlane(f0 + j);
      // post-ReLU values are >= 0 -> uint bit pattern is order-preserving
      atomicMax(ab + fu,             __float_as_uint(relu_(acc3[j] + b1[fu])));
      atomicMax(ab + NFILT + fu,     __float_as_uint(relu_(acc4[j] + b2[fu])));
      atomicMax(ab + 2 * NFILT + fu, __float_as_uint(relu_(acc5[j] + b3[fu])));
    }
  }
}

__global__ __launch_bounds__(256) void conv_max_kernel(
    const int* __restrict__ x, const float* __restrict__ emb,
    const float* __restrict__ w1, const float* __restrict__ b1,
    const float* __restrict__ w2, const float* __restrict__ b2,
    const float* __restrict__ w3, const float* __restrict__ b3,
    unsigned int* __restrict__ acc)
{
  const int lane  = threadIdx.x & 63;
  const int wave  = threadIdx.x >> 6;
  const int batch = blockIdx.y;
  const int f0    = blockIdx.z * (4 * FPW) + wave * FPW;
  const int t0_blk = blockIdx.x * BLK_POS;
  const int t0     = t0_blk + lane * QQ;

  // Gather the signal window [t0, t0+WIN) directly from emb.
  // t0 % 4 == 0 and DDIM % 4 == 0 -> float4-aligned; WIN=36 <= DDIM so the
  // window spans at most 2 embedding rows.
  float h[WIN];
  {
    int w0 = t0 / DDIM;
    int d0 = t0 - w0 * DDIM;                 // multiple of 4
    int wa = min(w0, NWORDS - 1);            // clamp: OOB lanes masked in TAIL path
    int wb = min(w0 + 1, NWORDS - 1);
    int xa = x[batch * NWORDS + wa];
    int xb = x[batch * NWORDS + wb];
    const float4* rowA = (const float4*)(emb + (size_t)xa * DDIM) + (d0 >> 2);
    const float4* rowB = (const float4*)(emb + (size_t)xb * DDIM);
    const int nf4 = (DDIM - d0) >> 2;        // float4s remaining in word A
    #pragma unroll
    for (int i = 0; i < WIN / 4; ++i) {
      const float4* src = (i < nf4) ? (rowA + i) : (rowB + (i - nf4));
      float4 v = *src;
      h[4*i+0] = v.x; h[4*i+1] = v.y; h[4*i+2] = v.z; h[4*i+3] = v.w;
    }
  }

  const bool tail = (t0_blk + BLK_POS + 4) > L_SIG;   // only block 439
  if (tail)
    run_filters<true >(h, t0, f0, batch, w1, b1, w2, b2, w3, b3, acc);
  else
    run_filters<false>(h, t0, f0, batch, w1, b1, w2, b2, w3, b3, acc);
}

// out[b][c] = sum_j feats[b][j] * fc_w[c][j] + fc_b[c];  feats = relu'd maxes in acc
__global__ void fc_kernel(const unsigned int* __restrict__ acc,
                          const float* __restrict__ fcw,
                          const float* __restrict__ fcb,
                          float* __restrict__ out)
{
  const int b = blockIdx.x / NCLS;
  const int c = blockIdx.x % NCLS;
  const int lane = threadIdx.x;
  float s = 0.0f;
  for (int j = lane; j < 3 * NFILT; j += 64)
    s += __uint_as_float(acc[b * 3 * NFILT + j]) * fcw[c * 3 * NFILT + j];
  #pragma unroll
  for (int k = 1; k < 64; k <<= 1) s += __shfl_xor(s, k);
  if (lane == 0) out[b * NCLS + c] = s + fcb[c];
}

extern "C" void kernel_launch(void* const* d_in, const int* in_sizes, int n_in,
                              void* d_out, int out_size, void* d_ws, size_t ws_size,
                              hipStream_t stream)
{
  const int*   x   = (const int*)  d_in[0];
  const float* emb = (const float*)d_in[1];
  const float* w1  = (const float*)d_in[2];
  const float* b1  = (const float*)d_in[3];
  const float* w2  = (const float*)d_in[4];
  const float* b2  = (const float*)d_in[5];
  const float* w3  = (const float*)d_in[6];
  const float* b3  = (const float*)d_in[7];
  const float* fcw = (const float*)d_in[8];
  const float* fcb = (const float*)d_in[9];
  float* out = (float*)d_out;

  unsigned int* acc = (unsigned int*)d_ws;   // [2][3][100] relu'd maxes as uint bits

  // ReLU output >= 0, so 0-init is the identity for the uint atomicMax.
  hipMemsetAsync(acc, 0, 2 * 3 * NFILT * sizeof(unsigned int), stream);

  dim3 grid(NBLK, 2, NGRP);
  conv_max_kernel<<<grid, 256, 0, stream>>>(x, emb, w1, b1, w2, b2, w3, b3, acc);
  fc_kernel<<<2 * NCLS, 64, 0, stream>>>(acc, fcw, fcb, out);
}

// Round 6
// 309.052 us; speedup vs baseline: 1.4312x; 1.1357x over previous
//
#include <hip/hip_runtime.h>

// Problem constants (from reference)
#define VOCAB   35097
#define DDIM    300
#define NWORDS  3000
#define L_SIG   900000          // DDIM * NWORDS
#define NFILT   100
#define NCLS    10

// Tiling.
//  - Grid (512, 2) = 1024 blocks of 256 threads = 4 blocks/CU: the WHOLE grid
//    is resident at once (no dispatch churn), balanced across CUs.
//  - Each wave: 25 filters = 5 groups x 5 filters. Group loop is `unroll 1`
//    (small I-footprint); filters inside a group are fully unrolled so the
//    15 running maxes are statically-indexed registers (runtime indexing ->
//    scratch; poisoned rounds 3/4).
//  - ONE butterfly reduce per group (15 independent chains, ILP-hidden) --
//    r2 paid a serialized reduce per filter; r5 paid 5x waves. This keeps
//    both fixes.
#define QQ      28
#define WIN     (QQ + 4)        // 32 floats per lane window
#define BLK_POS (64 * QQ)       // 1792 positions per block
#define NBLK    512             // blocks 503..511 early-exit; block 502 = TAIL
#define FPG     5               // filters per group (unrolled)
#define NGRPW   5               // groups per wave -> 25 filters/wave

__device__ __forceinline__ float relu_(float v) { return fmaxf(v, 0.0f); }

// One group: 5 filters x 3 conv sizes over the wave's 64*QQ tile.
// Weights via readfirstlane-uniform s_loads (proven r5: SGPRs, no spill).
// Bias+ReLU deferred past the max (both monotone).
template<bool TAIL>
__device__ __forceinline__ void run_group(
    const float (&h)[WIN], int t0, int f0, int batch, int lane,
    const float* __restrict__ w1, const float* __restrict__ b1,
    const float* __restrict__ w2, const float* __restrict__ b2,
    const float* __restrict__ w3, const float* __restrict__ b3,
    unsigned int* __restrict__ acc)
{
  int n3 = QQ, n4 = QQ, n5 = QQ;
  if (TAIL) {
    n3 = min(max(899998 - t0, 0), QQ);   // conv3 valid t <= 899997
    n4 = min(max(899997 - t0, 0), QQ);   // conv4 valid t <= 899996
    n5 = min(max(899996 - t0, 0), QQ);   // conv5 valid t <= 899995
  }
  const float NEG = -__builtin_huge_valf();

  float a3[FPG], a4[FPG], a5[FPG];       // static indexing only (full unroll)
  float bb3[FPG], bb4[FPG], bb5[FPG];

  #pragma unroll
  for (int j = 0; j < FPG; ++j) {
    const int fu = __builtin_amdgcn_readfirstlane(f0 + j);
    const float a0 = w1[fu*3+0], a1 = w1[fu*3+1], a2 = w1[fu*3+2];
    const float c0 = w2[fu*4+0], c1 = w2[fu*4+1], c2 = w2[fu*4+2], c3 = w2[fu*4+3];
    const float e0 = w3[fu*5+0], e1 = w3[fu*5+1], e2 = w3[fu*5+2], e3 = w3[fu*5+3], e4 = w3[fu*5+4];
    bb3[j] = b1[fu]; bb4[j] = b2[fu]; bb5[j] = b3[fu];

    float m3a = NEG, m3b = NEG, m4a = NEG, m4b = NEG, m5a = NEG, m5b = NEG;

    if (!TAIL) {
      // Pairs of positions; fmaxf(fmaxf(m,va),vb) fuses to v_max3_f32.
      #pragma unroll
      for (int p = 0; p < QQ; p += 2) {
        float v3a = fmaf(a0, h[p],   fmaf(a1, h[p+1], a2 * h[p+2]));
        float v3b = fmaf(a0, h[p+1], fmaf(a1, h[p+2], a2 * h[p+3]));
        if (((p >> 1) & 1) == 0) m3a = fmaxf(fmaxf(m3a, v3a), v3b);
        else                     m3b = fmaxf(fmaxf(m3b, v3a), v3b);
        float v4a = fmaf(c0, h[p],   fmaf(c1, h[p+1], fmaf(c2, h[p+2], c3 * h[p+3])));
        float v4b = fmaf(c0, h[p+1], fmaf(c1, h[p+2], fmaf(c2, h[p+3], c3 * h[p+4])));
        if (((p >> 1) & 1) == 0) m4a = fmaxf(fmaxf(m4a, v4a), v4b);
        else                     m4b = fmaxf(fmaxf(m4b, v4a), v4b);
        float v5a = fmaf(e0, h[p],   fmaf(e1, h[p+1], fmaf(e2, h[p+2], fmaf(e3, h[p+3], e4 * h[p+4]))));
        float v5b = fmaf(e0, h[p+1], fmaf(e1, h[p+2], fmaf(e2, h[p+3], fmaf(e3, h[p+4], e4 * h[p+5]))));
        if (((p >> 1) & 1) == 0) m5a = fmaxf(fmaxf(m5a, v5a), v5b);
        else                     m5b = fmaxf(fmaxf(m5b, v5a), v5b);
      }
    } else {
      #pragma unroll
      for (int p = 0; p < QQ; ++p) {
        float v3 = fmaf(a0, h[p], fmaf(a1, h[p+1], a2 * h[p+2]));
        float v4 = fmaf(c0, h[p], fmaf(c1, h[p+1], fmaf(c2, h[p+2], c3 * h[p+3])));
        float v5 = fmaf(e0, h[p], fmaf(e1, h[p+1], fmaf(e2, h[p+2], fmaf(e3, h[p+3], e4 * h[p+4]))));
        if (p < n3) { if (p & 1) m3b = fmaxf(m3b, v3); else m3a = fmaxf(m3a, v3); }
        if (p < n4) { if (p & 1) m4b = fmaxf(m4b, v4); else m4a = fmaxf(m4a, v4); }
        if (p < n5) { if (p & 1) m5b = fmaxf(m5b, v5); else m5a = fmaxf(m5a, v5); }
      }
    }
    a3[j] = fmaxf(m3a, m3b);
    a4[j] = fmaxf(m4a, m4b);
    a5[j] = fmaxf(m5a, m5b);
  }

  // ONE batched wave reduction per group: 15 independent 6-level chains.
  #pragma unroll
  for (int s = 1; s < 64; s <<= 1) {
    #pragma unroll
    for (int j = 0; j < FPG; ++j) {
      a3[j] = fmaxf(a3[j], __shfl_xor(a3[j], s));
      a4[j] = fmaxf(a4[j], __shfl_xor(a4[j], s));
      a5[j] = fmaxf(a5[j], __shfl_xor(a5[j], s));
    }
  }

  if (lane == 0) {
    unsigned int* ab = acc + batch * 3 * NFILT;
    #pragma unroll
    for (int j = 0; j < FPG; ++j) {
      const int f = f0 + j;
      // post-ReLU values are >= 0 -> uint bit pattern is order-preserving
      atomicMax(ab + f,             __float_as_uint(relu_(a3[j] + bb3[j])));
      atomicMax(ab + NFILT + f,     __float_as_uint(relu_(a4[j] + bb4[j])));
      atomicMax(ab + 2 * NFILT + f, __float_as_uint(relu_(a5[j] + bb5[j])));
    }
  }
}

__global__ __launch_bounds__(256, 4) void conv_max_kernel(
    const int* __restrict__ x, const float* __restrict__ emb,
    const float* __restrict__ w1, const float* __restrict__ b1,
    const float* __restrict__ w2, const float* __restrict__ b2,
    const float* __restrict__ w3, const float* __restrict__ b3,
    unsigned int* __restrict__ acc)
{
  const int t0_blk = blockIdx.x * BLK_POS;
  if (t0_blk >= 899998) return;            // blocks 503..511 idle

  const int lane  = threadIdx.x & 63;
  const int wave  = threadIdx.x >> 6;
  const int batch = blockIdx.y;
  const int t0    = t0_blk + lane * QQ;
  const int fbase = wave * (FPG * NGRPW);  // 25 filters per wave

  // Gather the signal window [t0, t0+WIN) directly from emb.
  // t0 % 4 == 0 and DDIM % 4 == 0 -> float4-aligned; WIN=32 <= DDIM so the
  // window spans at most 2 embedding rows. OOB lanes clamp (masked by TAIL).
  float h[WIN];
  {
    int w0 = t0 / DDIM;
    int d0 = t0 - w0 * DDIM;                 // multiple of 4
    int wa = min(w0, NWORDS - 1);
    int wb = min(w0 + 1, NWORDS - 1);
    int xa = x[batch * NWORDS + wa];
    int xb = x[batch * NWORDS + wb];
    const float4* rowA = (const float4*)(emb + (size_t)xa * DDIM) + (d0 >> 2);
    const float4* rowB = (const float4*)(emb + (size_t)xb * DDIM);
    const int nf4 = (DDIM - d0) >> 2;        // float4s remaining in word A
    #pragma unroll
    for (int i = 0; i < WIN / 4; ++i) {
      const float4* src = (i < nf4) ? (rowA + i) : (rowB + (i - nf4));
      float4 v = *src;
      h[4*i+0] = v.x; h[4*i+1] = v.y; h[4*i+2] = v.z; h[4*i+3] = v.w;
    }
  }

  const bool tail = (t0_blk + BLK_POS + 4) > L_SIG;   // only block 502
  if (tail) {
    #pragma unroll 1
    for (int g = 0; g < NGRPW; ++g)
      run_group<true >(h, t0, fbase + g * FPG, batch, lane, w1, b1, w2, b2, w3, b3, acc);
  } else {
    #pragma unroll 1
    for (int g = 0; g < NGRPW; ++g)
      run_group<false>(h, t0, fbase + g * FPG, batch, lane, w1, b1, w2, b2, w3, b3, acc);
  }
}

// out[b][c] = sum_j feats[b][j] * fc_w[c][j] + fc_b[c];  feats = relu'd maxes in acc
__global__ void fc_kernel(const unsigned int* __restrict__ acc,
                          const float* __restrict__ fcw,
                          const float* __restrict__ fcb,
                          float* __restrict__ out)
{
  const int b = blockIdx.x / NCLS;
  const int c = blockIdx.x % NCLS;
  const int lane = threadIdx.x;
  float s = 0.0f;
  for (int j = lane; j < 3 * NFILT; j += 64)
    s += __uint_as_float(acc[b * 3 * NFILT + j]) * fcw[c * 3 * NFILT + j];
  #pragma unroll
  for (int k = 1; k < 64; k <<= 1) s += __shfl_xor(s, k);
  if (lane == 0) out[b * NCLS + c] = s + fcb[c];
}

extern "C" void kernel_launch(void* const* d_in, const int* in_sizes, int n_in,
                              void* d_out, int out_size, void* d_ws, size_t ws_size,
                              hipStream_t stream)
{
  const int*   x   = (const int*)  d_in[0];
  const float* emb = (const float*)d_in[1];
  const float* w1  = (const float*)d_in[2];
  const float* b1  = (const float*)d_in[3];
  const float* w2  = (const float*)d_in[4];
  const float* b2  = (const float*)d_in[5];
  const float* w3  = (const float*)d_in[6];
  const float* b3  = (const float*)d_in[7];
  const float* fcw = (const float*)d_in[8];
  const float* fcb = (const float*)d_in[9];
  float* out = (float*)d_out;

  unsigned int* acc = (unsigned int*)d_ws;   // [2][3][100] relu'd maxes as uint bits

  // ReLU output >= 0, so 0-init is the identity for the uint atomicMax.
  hipMemsetAsync(acc, 0, 2 * 3 * NFILT * sizeof(unsigned int), stream);

  dim3 grid(NBLK, 2);
  conv_max_kernel<<<grid, 256, 0, stream>>>(x, emb, w1, b1, w2, b2, w3, b3, acc);
  fc_kernel<<<2 * NCLS, 64, 0, stream>>>(acc, fcw, fcb, out);
}

// Round 7
// 181.056 us; speedup vs baseline: 2.4430x; 1.7069x over previous
//
#include <hip/hip_runtime.h>

// Problem constants (from reference)
#define VOCAB   35097
#define DDIM    300
#define NWORDS  3000
#define L_SIG   900000          // DDIM * NWORDS
#define NFILT   100
#define NCLS    10

// Tiling (r6 structure, minus atomics).
//  - QQ positions/lane; 5 groups x 5 filters per wave (statically unrolled
//    accumulators -- runtime indexing spills, proven r3/r4).
//  - Grid x = 503 ACTIVE blocks only (every partial slot gets written; the
//    harness poisons d_ws, so no slot may be left unwritten).
//  - NO global atomics: each wave stores its 75 raw maxes to a private slot
//    partial[b][blk][wave*75..+75]; a second tiny kernel reduces over blk.
//    (r2-r6 all paid ~300K device-scope atomicMax on 600 words from 8 XCDs;
//    the ~100K-cycle/wave un-hidden stall was invariant across structures --
//    prime suspect is that atomic serialization + retire-drain backpressure.)
#define QQ      28
#define WIN     (QQ + 4)        // 32 floats per lane window
#define BLK_POS (64 * QQ)       // 1792 positions per block
#define NBLKA   503             // ceil(899998 / 1792); block 502 = TAIL
#define FPG     5               // filters per group (unrolled)
#define NGRPW   5               // groups per wave -> 25 filters/wave

__device__ __forceinline__ float relu_(float v) { return fmaxf(v, 0.0f); }

// One group: 5 filters x 3 conv sizes over the wave's 64*QQ tile.
// Weights via readfirstlane-uniform s_loads (SGPRs, no spill -- proven r5/r6).
// Raw maxes only; bias+ReLU deferred to reduce_kernel (monotone).
template<bool TAIL>
__device__ __forceinline__ void run_group(
    const float (&h)[WIN], int t0, int f0, int lane,
    const float* __restrict__ w1, const float* __restrict__ w2,
    const float* __restrict__ w3,
    float* __restrict__ pslot)   // partial + [b][blk][wave*75 + g*15]
{
  int n3 = QQ, n4 = QQ, n5 = QQ;
  if (TAIL) {
    n3 = min(max(899998 - t0, 0), QQ);   // conv3 valid t <= 899997
    n4 = min(max(899997 - t0, 0), QQ);   // conv4 valid t <= 899996
    n5 = min(max(899996 - t0, 0), QQ);   // conv5 valid t <= 899995
  }
  const float NEG = -__builtin_huge_valf();

  float a3[FPG], a4[FPG], a5[FPG];       // static indexing only (full unroll)

  #pragma unroll
  for (int j = 0; j < FPG; ++j) {
    const int fu = __builtin_amdgcn_readfirstlane(f0 + j);
    const float a0 = w1[fu*3+0], a1 = w1[fu*3+1], a2 = w1[fu*3+2];
    const float c0 = w2[fu*4+0], c1 = w2[fu*4+1], c2 = w2[fu*4+2], c3 = w2[fu*4+3];
    const float e0 = w3[fu*5+0], e1 = w3[fu*5+1], e2 = w3[fu*5+2], e3 = w3[fu*5+3], e4 = w3[fu*5+4];

    float m3a = NEG, m3b = NEG, m4a = NEG, m4b = NEG, m5a = NEG, m5b = NEG;

    if (!TAIL) {
      // Pairs of positions; fmaxf(fmaxf(m,va),vb) fuses to v_max3_f32.
      #pragma unroll
      for (int p = 0; p < QQ; p += 2) {
        float v3a = fmaf(a0, h[p],   fmaf(a1, h[p+1], a2 * h[p+2]));
        float v3b = fmaf(a0, h[p+1], fmaf(a1, h[p+2], a2 * h[p+3]));
        if (((p >> 1) & 1) == 0) m3a = fmaxf(fmaxf(m3a, v3a), v3b);
        else                     m3b = fmaxf(fmaxf(m3b, v3a), v3b);
        float v4a = fmaf(c0, h[p],   fmaf(c1, h[p+1], fmaf(c2, h[p+2], c3 * h[p+3])));
        float v4b = fmaf(c0, h[p+1], fmaf(c1, h[p+2], fmaf(c2, h[p+3], c3 * h[p+4])));
        if (((p >> 1) & 1) == 0) m4a = fmaxf(fmaxf(m4a, v4a), v4b);
        else                     m4b = fmaxf(fmaxf(m4b, v4a), v4b);
        float v5a = fmaf(e0, h[p],   fmaf(e1, h[p+1], fmaf(e2, h[p+2], fmaf(e3, h[p+3], e4 * h[p+4]))));
        float v5b = fmaf(e0, h[p+1], fmaf(e1, h[p+2], fmaf(e2, h[p+3], fmaf(e3, h[p+4], e4 * h[p+5]))));
        if (((p >> 1) & 1) == 0) m5a = fmaxf(fmaxf(m5a, v5a), v5b);
        else                     m5b = fmaxf(fmaxf(m5b, v5a), v5b);
      }
    } else {
      #pragma unroll
      for (int p = 0; p < QQ; ++p) {
        float v3 = fmaf(a0, h[p], fmaf(a1, h[p+1], a2 * h[p+2]));
        float v4 = fmaf(c0, h[p], fmaf(c1, h[p+1], fmaf(c2, h[p+2], c3 * h[p+3])));
        float v5 = fmaf(e0, h[p], fmaf(e1, h[p+1], fmaf(e2, h[p+2], fmaf(e3, h[p+3], e4 * h[p+4]))));
        if (p < n3) { if (p & 1) m3b = fmaxf(m3b, v3); else m3a = fmaxf(m3a, v3); }
        if (p < n4) { if (p & 1) m4b = fmaxf(m4b, v4); else m4a = fmaxf(m4a, v4); }
        if (p < n5) { if (p & 1) m5b = fmaxf(m5b, v5); else m5a = fmaxf(m5a, v5); }
      }
    }
    a3[j] = fmaxf(m3a, m3b);
    a4[j] = fmaxf(m4a, m4b);
    a5[j] = fmaxf(m5a, m5b);
  }

  // ONE batched wave reduction per group: 15 independent 6-level chains.
  #pragma unroll
  for (int s = 1; s < 64; s <<= 1) {
    #pragma unroll
    for (int j = 0; j < FPG; ++j) {
      a3[j] = fmaxf(a3[j], __shfl_xor(a3[j], s));
      a4[j] = fmaxf(a4[j], __shfl_xor(a4[j], s));
      a5[j] = fmaxf(a5[j], __shfl_xor(a5[j], s));
    }
  }

  // Plain stores to a wave-private slot: 15 consecutive floats -> ~1 line.
  // No contention, no RMW, fast retire.
  if (lane == 0) {
    #pragma unroll
    for (int j = 0; j < FPG; ++j) {
      pslot[j]      = a3[j];
      pslot[5 + j]  = a4[j];
      pslot[10 + j] = a5[j];
    }
  }
}

__global__ __launch_bounds__(256, 4) void conv_max_kernel(
    const int* __restrict__ x, const float* __restrict__ emb,
    const float* __restrict__ w1, const float* __restrict__ w2,
    const float* __restrict__ w3,
    float* __restrict__ partial)      // [2][NBLKA][300]
{
  const int lane  = threadIdx.x & 63;
  const int wave  = threadIdx.x >> 6;
  const int batch = blockIdx.y;
  const int t0_blk = blockIdx.x * BLK_POS;
  const int t0     = t0_blk + lane * QQ;
  const int fbase  = wave * (FPG * NGRPW);  // 25 filters per wave

  // Gather the signal window [t0, t0+WIN) directly from emb.
  // t0 % 4 == 0 and DDIM % 4 == 0 -> float4-aligned; WIN=32 <= DDIM so the
  // window spans at most 2 embedding rows. OOB lanes clamp (TAIL masks them;
  // their raw max stays -inf, absorbed by the block/column max).
  float h[WIN];
  {
    int w0 = t0 / DDIM;
    int d0 = t0 - w0 * DDIM;                 // multiple of 4
    int wa = min(w0, NWORDS - 1);
    int wb = min(w0 + 1, NWORDS - 1);
    int xa = x[batch * NWORDS + wa];
    int xb = x[batch * NWORDS + wb];
    const float4* rowA = (const float4*)(emb + (size_t)xa * DDIM) + (d0 >> 2);
    const float4* rowB = (const float4*)(emb + (size_t)xb * DDIM);
    const int nf4 = (DDIM - d0) >> 2;        // float4s remaining in word A
    #pragma unroll
    for (int i = 0; i < WIN / 4; ++i) {
      const float4* src = (i < nf4) ? (rowA + i) : (rowB + (i - nf4));
      float4 v = *src;
      h[4*i+0] = v.x; h[4*i+1] = v.y; h[4*i+2] = v.z; h[4*i+3] = v.w;
    }
  }

  float* pwave = partial + ((size_t)batch * NBLKA + blockIdx.x) * 300 + wave * (FPG * 3 * NGRPW / NGRPW) * NGRPW; // wave*75
  // (simplify: wave*75)
  pwave = partial + ((size_t)batch * NBLKA + blockIdx.x) * 300 + wave * 75;

  const bool tail = (t0_blk + BLK_POS + 4) > L_SIG;   // only block 502
  if (tail) {
    #pragma unroll 1
    for (int g = 0; g < NGRPW; ++g)
      run_group<true >(h, t0, fbase + g * FPG, lane, w1, w2, w3, pwave + g * 15);
  } else {
    #pragma unroll 1
    for (int g = 0; g < NGRPW; ++g)
      run_group<false>(h, t0, fbase + g * FPG, lane, w1, w2, w3, pwave + g * 15);
  }
}

// Reduce partial[b][blk][p] over blk, apply bias+ReLU, write feats[b][300]
// in reference concat order (conv3 | conv4 | conv5).
__global__ void reduce_kernel(const float* __restrict__ partial,
                              const float* __restrict__ b1,
                              const float* __restrict__ b2,
                              const float* __restrict__ b3,
                              float* __restrict__ feats)
{
  const int p    = blockIdx.x;          // 0..299 position within a block slot
  const int b    = threadIdx.x >> 6;    // wave 0/1 (128 threads)
  const int lane = threadIdx.x & 63;

  // Decode p -> (conv, filter): p = wave*75 + g*15 + conv*5 + j
  const int wv = p / 75, r = p % 75, g = r / 15, q = r % 15;
  const int conv = q / 5, j = q % 5;
  const int f = wv * 25 + g * 5 + j;

  const float* col = partial + (size_t)b * NBLKA * 300 + p;
  float m = -__builtin_huge_valf();
  for (int i = lane; i < NBLKA; i += 64)
    m = fmaxf(m, col[(size_t)i * 300]);
  #pragma unroll
  for (int s = 1; s < 64; s <<= 1)
    m = fmaxf(m, __shfl_xor(m, s));

  if (lane == 0) {
    const float bias = (conv == 0) ? b1[f] : (conv == 1) ? b2[f] : b3[f];
    feats[b * 300 + conv * NFILT + f] = relu_(m + bias);
  }
}

// out[b][c] = sum_k feats[b][k] * fc_w[c][k] + fc_b[c]
__global__ void fc_kernel(const float* __restrict__ feats,
                          const float* __restrict__ fcw,
                          const float* __restrict__ fcb,
                          float* __restrict__ out)
{
  const int b = blockIdx.x / NCLS;
  const int c = blockIdx.x % NCLS;
  const int lane = threadIdx.x;
  float s = 0.0f;
  for (int k = lane; k < 3 * NFILT; k += 64)
    s += feats[b * 3 * NFILT + k] * fcw[c * 3 * NFILT + k];
  #pragma unroll
  for (int k = 1; k < 64; k <<= 1) s += __shfl_xor(s, k);
  if (lane == 0) out[b * NCLS + c] = s + fcb[c];
}

extern "C" void kernel_launch(void* const* d_in, const int* in_sizes, int n_in,
                              void* d_out, int out_size, void* d_ws, size_t ws_size,
                              hipStream_t stream)
{
  const int*   x   = (const int*)  d_in[0];
  const float* emb = (const float*)d_in[1];
  const float* w1  = (const float*)d_in[2];
  const float* b1  = (const float*)d_in[3];
  const float* w2  = (const float*)d_in[4];
  const float* b2  = (const float*)d_in[5];
  const float* w3  = (const float*)d_in[6];
  const float* b3  = (const float*)d_in[7];
  const float* fcw = (const float*)d_in[8];
  const float* fcb = (const float*)d_in[9];
  float* out = (float*)d_out;

  // Workspace: partial [2][503][300] floats, then feats [2][300].
  float* partial = (float*)d_ws;                       // 1.207 MB
  float* feats   = partial + (size_t)2 * NBLKA * 300;  // +2.4 KB

  dim3 grid(NBLKA, 2);
  conv_max_kernel<<<grid, 256, 0, stream>>>(x, emb, w1, w2, w3, partial);
  reduce_kernel<<<300, 128, 0, stream>>>(partial, b1, b2, b3, feats);
  fc_kernel<<<2 * NCLS, 64, 0, stream>>>(feats, fcw, fcb, out);
}

// Round 8
// 171.246 us; speedup vs baseline: 2.5830x; 1.0573x over previous
//
#include <hip/hip_runtime.h>

// Problem constants (from reference)
#define VOCAB   35097
#define DDIM    300
#define NWORDS  3000
#define L_SIG   900000          // DDIM * NWORDS
#define NFILT   100
#define NCLS    10

// Tiling (r7 structure + packed-FP32 inner loop + transposed partial).
#define QQ      28
#define HALF    14              // lane packs positions (p, p+HALF) per pk op
#define WIN     (QQ + 4)        // 32 floats per lane window
#define NHP     (HALF + 4)      // 18 packed float2 window entries
#define BLK_POS (64 * QQ)       // 1792 positions per block
#define NBLKA   503             // ceil(899998 / 1792); block 502 = TAIL
#define NBLKP   512             // padded row length of partial[b][p][*]
#define FPG     5               // filters per group (unrolled; static acc)
#define NGRPW   5               // groups per wave -> 25 filters/wave

typedef __attribute__((ext_vector_type(2))) float f32x2;

__device__ __forceinline__ float relu_(float v) { return fmaxf(v, 0.0f); }

// Packed FP32: 2 FMAs / instruction (v_pk_* exist since gfx90a).
// Operands are 64-bit (VGPR pairs); weight pairs are pre-duplicated {w,w}.
__device__ __forceinline__ f32x2 pk_mul(f32x2 a, f32x2 b) {
  f32x2 d;
  asm("v_pk_mul_f32 %0, %1, %2" : "=v"(d) : "v"(a), "v"(b));
  return d;
}
__device__ __forceinline__ f32x2 pk_fma(f32x2 a, f32x2 b, f32x2 c) {
  f32x2 d;
  asm("v_pk_fma_f32 %0, %1, %2, %3" : "=v"(d) : "v"(a), "v"(b), "v"(c));
  return d;
}
__device__ __forceinline__ f32x2 dup2(float w) { f32x2 d; d.x = w; d.y = w; return d; }

// One group: FPG filters x 3 conv sizes over the wave's 64*QQ tile.
// Non-TAIL: packed path, positions (p, p+HALF) per pk instruction.
// TAIL (block 502 only): r7's scalar path with per-position masking.
// Raw maxes only; bias+ReLU deferred to reduce_kernel (monotone).
template<bool TAIL>
__device__ __forceinline__ void run_group(
    const float (&h)[WIN], const f32x2 (&hp)[NHP], int t0, int f0, int lane,
    const float* __restrict__ w1, const float* __restrict__ w2,
    const float* __restrict__ w3,
    float* __restrict__ pslot)   // partial row base: 15 rows of NBLKP
{
  int n3 = QQ, n4 = QQ, n5 = QQ;
  if (TAIL) {
    n3 = min(max(899998 - t0, 0), QQ);   // conv3 valid t <= 899997
    n4 = min(max(899997 - t0, 0), QQ);   // conv4 valid t <= 899996
    n5 = min(max(899996 - t0, 0), QQ);   // conv5 valid t <= 899995
  }
  const float NEG = -__builtin_huge_valf();

  float a3[FPG], a4[FPG], a5[FPG];       // static indexing only (full unroll)

  #pragma unroll
  for (int j = 0; j < FPG; ++j) {
    const int fu = __builtin_amdgcn_readfirstlane(f0 + j);
    const float a0 = w1[fu*3+0], a1 = w1[fu*3+1], a2 = w1[fu*3+2];
    const float c0 = w2[fu*4+0], c1 = w2[fu*4+1], c2 = w2[fu*4+2], c3 = w2[fu*4+3];
    const float e0 = w3[fu*5+0], e1 = w3[fu*5+1], e2 = w3[fu*5+2], e3 = w3[fu*5+3], e4 = w3[fu*5+4];

    float m3a = NEG, m3b = NEG, m4a = NEG, m4b = NEG, m5a = NEG, m5b = NEG;

    if (!TAIL) {
      // Duplicate weights into VGPR pairs once per filter.
      const f32x2 pa0 = dup2(a0), pa1 = dup2(a1), pa2 = dup2(a2);
      const f32x2 pc0 = dup2(c0), pc1 = dup2(c1), pc2 = dup2(c2), pc3 = dup2(c3);
      const f32x2 pe0 = dup2(e0), pe1 = dup2(e1), pe2 = dup2(e2), pe3 = dup2(e3), pe4 = dup2(e4);

      #pragma unroll
      for (int p = 0; p < HALF; ++p) {
        // Each pk op computes the conv at positions p (lo) and p+HALF (hi).
        f32x2 t3 = pk_mul(pa2, hp[p+2]);
        t3 = pk_fma(pa1, hp[p+1], t3);
        t3 = pk_fma(pa0, hp[p+0], t3);
        f32x2 t4 = pk_mul(pc3, hp[p+3]);
        t4 = pk_fma(pc2, hp[p+2], t4);
        t4 = pk_fma(pc1, hp[p+1], t4);
        t4 = pk_fma(pc0, hp[p+0], t4);
        f32x2 t5 = pk_mul(pe4, hp[p+4]);
        t5 = pk_fma(pe3, hp[p+3], t5);
        t5 = pk_fma(pe2, hp[p+2], t5);
        t5 = pk_fma(pe1, hp[p+1], t5);
        t5 = pk_fma(pe0, hp[p+0], t5);
        // fmaxf(fmaxf(m, x), y) fuses to v_max3_f32; alternate accumulators.
        if (p & 1) {
          m3b = fmaxf(fmaxf(m3b, t3.x), t3.y);
          m4b = fmaxf(fmaxf(m4b, t4.x), t4.y);
          m5b = fmaxf(fmaxf(m5b, t5.x), t5.y);
        } else {
          m3a = fmaxf(fmaxf(m3a, t3.x), t3.y);
          m4a = fmaxf(fmaxf(m4a, t4.x), t4.y);
          m5a = fmaxf(fmaxf(m5a, t5.x), t5.y);
        }
      }
    } else {
      #pragma unroll
      for (int p = 0; p < QQ; ++p) {
        float v3 = fmaf(a0, h[p], fmaf(a1, h[p+1], a2 * h[p+2]));
        float v4 = fmaf(c0, h[p], fmaf(c1, h[p+1], fmaf(c2, h[p+2], c3 * h[p+3])));
        float v5 = fmaf(e0, h[p], fmaf(e1, h[p+1], fmaf(e2, h[p+2], fmaf(e3, h[p+3], e4 * h[p+4]))));
        if (p < n3) { if (p & 1) m3b = fmaxf(m3b, v3); else m3a = fmaxf(m3a, v3); }
        if (p < n4) { if (p & 1) m4b = fmaxf(m4b, v4); else m4a = fmaxf(m4a, v4); }
        if (p < n5) { if (p & 1) m5b = fmaxf(m5b, v5); else m5a = fmaxf(m5a, v5); }
      }
    }
    a3[j] = fmaxf(m3a, m3b);
    a4[j] = fmaxf(m4a, m4b);
    a5[j] = fmaxf(m5a, m5b);
  }

  // ONE batched wave reduction per group: 15 independent 6-level chains.
  #pragma unroll
  for (int s = 1; s < 64; s <<= 1) {
    #pragma unroll
    for (int j = 0; j < FPG; ++j) {
      a3[j] = fmaxf(a3[j], __shfl_xor(a3[j], s));
      a4[j] = fmaxf(a4[j], __shfl_xor(a4[j], s));
      a5[j] = fmaxf(a5[j], __shfl_xor(a5[j], s));
    }
  }

  // Plain stores, wave-private slots. Transposed layout [b][p][blk]: rows are
  // contiguous in blk so reduce_kernel reads coalesced (r7's column reads
  // touched 503 cache lines per (b,p) -> ~19 MB of L2 line traffic).
  if (lane == 0) {
    #pragma unroll
    for (int j = 0; j < FPG; ++j) {
      pslot[(size_t)(j)      * NBLKP] = a3[j];
      pslot[(size_t)(5 + j)  * NBLKP] = a4[j];
      pslot[(size_t)(10 + j) * NBLKP] = a5[j];
    }
  }
}

__global__ __launch_bounds__(256, 4) void conv_max_kernel(
    const int* __restrict__ x, const float* __restrict__ emb,
    const float* __restrict__ w1, const float* __restrict__ w2,
    const float* __restrict__ w3,
    float* __restrict__ partial)      // [2][300][NBLKP]
{
  const int lane  = threadIdx.x & 63;
  const int wave  = threadIdx.x >> 6;
  const int batch = blockIdx.y;
  const int t0_blk = blockIdx.x * BLK_POS;
  const int t0     = t0_blk + lane * QQ;
  const int fbase  = wave * (FPG * NGRPW);  // 25 filters per wave

  // Gather the signal window [t0, t0+WIN) directly from emb.
  // t0 % 4 == 0 and DDIM % 4 == 0 -> float4-aligned; WIN=32 <= DDIM so the
  // window spans at most 2 embedding rows. OOB lanes clamp (TAIL masks them).
  float h[WIN];
  {
    int w0 = t0 / DDIM;
    int d0 = t0 - w0 * DDIM;                 // multiple of 4
    int wa = min(w0, NWORDS - 1);
    int wb = min(w0 + 1, NWORDS - 1);
    int xa = x[batch * NWORDS + wa];
    int xb = x[batch * NWORDS + wb];
    const float4* rowA = (const float4*)(emb + (size_t)xa * DDIM) + (d0 >> 2);
    const float4* rowB = (const float4*)(emb + (size_t)xb * DDIM);
    const int nf4 = (DDIM - d0) >> 2;        // float4s remaining in word A
    #pragma unroll
    for (int i = 0; i < WIN / 4; ++i) {
      const float4* src = (i < nf4) ? (rowA + i) : (rowB + (i - nf4));
      float4 v = *src;
      h[4*i+0] = v.x; h[4*i+1] = v.y; h[4*i+2] = v.z; h[4*i+3] = v.w;
    }
  }

  // Pack distant-position pairs for v_pk ops: hp[k] = {h[k], h[k+HALF]}.
  f32x2 hp[NHP];
  #pragma unroll
  for (int k = 0; k < NHP; ++k) { f32x2 t; t.x = h[k]; t.y = h[k + HALF]; hp[k] = t; }

  // partial row base for this wave: rows are p = wave*75 + g*15 + (conv*5+j).
  float* prow = partial + ((size_t)batch * 300 + wave * 75) * NBLKP + blockIdx.x;

  const bool tail = (t0_blk + BLK_POS + 4) > L_SIG;   // only block 502
  if (tail) {
    #pragma unroll 1
    for (int g = 0; g < NGRPW; ++g)
      run_group<true >(h, hp, t0, fbase + g * FPG, lane, w1, w2, w3,
                       prow + (size_t)g * 15 * NBLKP);
  } else {
    #pragma unroll 1
    for (int g = 0; g < NGRPW; ++g)
      run_group<false>(h, hp, t0, fbase + g * FPG, lane, w1, w2, w3,
                       prow + (size_t)g * 15 * NBLKP);
  }
}

// Reduce partial[b][p][blk] over blk (contiguous, coalesced), apply bias+ReLU,
// write feats[b][300] in reference concat order (conv3 | conv4 | conv5).
__global__ void reduce_kernel(const float* __restrict__ partial,
                              const float* __restrict__ b1,
                              const float* __restrict__ b2,
                              const float* __restrict__ b3,
                              float* __restrict__ feats)
{
  const int idx  = blockIdx.x;          // 0..599 = b*300 + p
  const int b    = idx / 300;
  const int p    = idx % 300;
  const int lane = threadIdx.x;

  // Decode p -> (conv, filter): p = wave*75 + g*15 + conv*5 + j
  const int wv = p / 75, r = p % 75, g = r / 15, q = r % 15;
  const int conv = q / 5, j = q % 5;
  const int f = wv * 25 + g * 5 + j;

  const float* row = partial + ((size_t)b * 300 + p) * NBLKP;
  float m = -__builtin_huge_valf();
  for (int i = lane; i < NBLKA; i += 64)
    m = fmaxf(m, row[i]);
  #pragma unroll
  for (int s = 1; s < 64; s <<= 1)
    m = fmaxf(m, __shfl_xor(m, s));

  if (lane == 0) {
    const float bias = (conv == 0) ? b1[f] : (conv == 1) ? b2[f] : b3[f];
    feats[b * 300 + conv * NFILT + f] = relu_(m + bias);
  }
}

// out[b][c] = sum_k feats[b][k] * fc_w[c][k] + fc_b[c]
__global__ void fc_kernel(const float* __restrict__ feats,
                          const float* __restrict__ fcw,
                          const float* __restrict__ fcb,
                          float* __restrict__ out)
{
  const int b = blockIdx.x / NCLS;
  const int c = blockIdx.x % NCLS;
  const int lane = threadIdx.x;
  float s = 0.0f;
  for (int k = lane; k < 3 * NFILT; k += 64)
    s += feats[b * 3 * NFILT + k] * fcw[c * 3 * NFILT + k];
  #pragma unroll
  for (int k = 1; k < 64; k <<= 1) s += __shfl_xor(s, k);
  if (lane == 0) out[b * NCLS + c] = s + fcb[c];
}

extern "C" void kernel_launch(void* const* d_in, const int* in_sizes, int n_in,
                              void* d_out, int out_size, void* d_ws, size_t ws_size,
                              hipStream_t stream)
{
  const int*   x   = (const int*)  d_in[0];
  const float* emb = (const float*)d_in[1];
  const float* w1  = (const float*)d_in[2];
  const float* b1  = (const float*)d_in[3];
  const float* w2  = (const float*)d_in[4];
  const float* b2  = (const float*)d_in[5];
  const float* w3  = (const float*)d_in[6];
  const float* b3  = (const float*)d_in[7];
  const float* fcw = (const float*)d_in[8];
  const float* fcb = (const float*)d_in[9];
  float* out = (float*)d_out;

  // Workspace: partial [2][300][NBLKP] floats, then feats [2][300].
  float* partial = (float*)d_ws;                        // 1.229 MB
  float* feats   = partial + (size_t)2 * 300 * NBLKP;   // +2.4 KB

  dim3 grid(NBLKA, 2);
  conv_max_kernel<<<grid, 256, 0, stream>>>(x, emb, w1, w2, w3, partial);
  reduce_kernel<<<600, 64, 0, stream>>>(partial, b1, b2, b3, feats);
  fc_kernel<<<2 * NCLS, 64, 0, stream>>>(feats, fcw, fcb, out);
}